// Round 8
// baseline (148.306 us; speedup 1.0000x reference)
//
#include <hip/hip_runtime.h>
#include <stdint.h>

#define B_     4
#define A_     9
#define H_     50
#define W_     76
#define N_     (H_ * W_ * A_)   // 34200
#define PRE_   6000
#define POST_  300
#define NBIN   65536
#define NSEG   256
#define SKCAP  8192
#define ACTMAX 256
#define FXCAP  2048
#define NW_    47               // ceil(PRE_/128)

// generate_anchors(16) precomputed (exact, verified against the numpy code)
__constant__ float c_anchors[9][4] = {
    { -84.f,  -40.f,  99.f,  55.f},
    {-176.f,  -88.f, 191.f, 103.f},
    {-360.f, -184.f, 375.f, 199.f},
    { -56.f,  -56.f,  71.f,  71.f},
    {-120.f, -120.f, 135.f, 135.f},
    {-248.f, -248.f, 263.f, 263.f},
    { -36.f,  -80.f,  51.f,  95.f},
    { -80.f, -168.f,  95.f, 183.f},
    {-168.f, -344.f, 183.f, 359.f},
};

// composite key: (~score_bits)<<32 | n  — ascending key == descending score, ascending idx
__device__ __forceinline__ unsigned long long make_key(const float* __restrict__ scores,
                                                       int idx, int* pb) {
    int w = idx % W_;
    int h = (idx / W_) % H_;
    int a = (idx / (W_ * H_)) % A_;
    int b = idx / (W_ * H_ * A_);
    float s = scores[(((b * 2 * A_) + A_ + a) * H_ + h) * W_ + w];
    unsigned int sb = __float_as_uint(s);          // s >= 0 -> monotone bits
    unsigned int n  = (unsigned int)((h * W_ + w) * A_ + a);
    *pb = b;
    return (((unsigned long long)(~sb)) << 32) | (unsigned long long)n;
}

// ---- kernel 1: 16-bit-prefix histogram of keys
__global__ void k_hist(const float* __restrict__ scores,
                       unsigned int* __restrict__ hist) {
    int idx = blockIdx.x * 256 + threadIdx.x;
    if (idx >= B_ * N_) return;
    int b;
    unsigned long long key = make_key(scores, idx, &b);
    atomicAdd(&hist[b * NBIN + (unsigned int)(key >> 48)], 1u);
}

// ---- kernel 2a: per-segment sums (coalesced), 256 bins per block
__global__ __launch_bounds__(256) void k_prefix1(const unsigned int* __restrict__ hist,
                                                 unsigned int* __restrict__ segsum) {
    int b = blockIdx.y, seg = blockIdx.x, tid = threadIdx.x;
    int lane = tid & 63, wid = tid >> 6;
    unsigned int v = hist[b * NBIN + seg * 256 + tid];
#pragma unroll
    for (int off = 32; off > 0; off >>= 1) v += __shfl_down(v, off);
    __shared__ unsigned int wsum[4];
    if (lane == 0) wsum[wid] = v;
    __syncthreads();
    if (tid == 0) segsum[b * NSEG + seg] = wsum[0] + wsum[1] + wsum[2] + wsum[3];
}

// ---- kernel 2b: exclusive scan of the 256 segment sums (1 block/image)
__global__ __launch_bounds__(256) void k_prefix2(const unsigned int* __restrict__ segsum,
                                                 unsigned int* __restrict__ segbase) {
    int b = blockIdx.x, tid = threadIdx.x;
    __shared__ unsigned int sp[256];
    unsigned int own = segsum[b * NSEG + tid];
    sp[tid] = own;
    __syncthreads();
    for (int off = 1; off < 256; off <<= 1) {
        unsigned int v = (tid >= off) ? sp[tid - off] : 0u;
        __syncthreads();
        sp[tid] += v;
        __syncthreads();
    }
    segbase[b * NSEG + tid] = sp[tid] - own;   // exclusive
}

// ---- kernel 2c: intra-segment exclusive scan + segbase; coalesced prefix writes;
//      append active buckets (cnt>0 && start<PRE_)
__global__ __launch_bounds__(256) void k_prefix3(unsigned int* __restrict__ hist,
                                                 const unsigned int* __restrict__ segbase,
                                                 unsigned int* __restrict__ prefw,
                                                 unsigned int* __restrict__ actA,
                                                 unsigned int* __restrict__ actB,
                                                 unsigned int* __restrict__ actcnt) {
    int b = blockIdx.y, seg = blockIdx.x, tid = threadIdx.x;
    int bin = seg * 256 + tid;
    unsigned int c = hist[b * NBIN + bin];
    __shared__ unsigned int sp[256];
    sp[tid] = c;
    __syncthreads();
    for (int off = 1; off < 256; off <<= 1) {
        unsigned int v = (tid >= off) ? sp[tid - off] : 0u;
        __syncthreads();
        sp[tid] += v;
        __syncthreads();
    }
    unsigned int run = segbase[b * NSEG + seg] + sp[tid] - c;   // global exclusive prefix
    hist[b * NBIN + bin]  = run;    // static prefix (coalesced)
    prefw[b * NBIN + bin] = run;    // working prefix (coalesced)
    if (c > 0 && run < (unsigned int)PRE_) {
        unsigned int pos = atomicAdd(&actcnt[b], 1u);
        if (pos < ACTMAX) {
            actA[b * ACTMAX + pos] = run;
            actB[b * ACTMAX + pos] = ((unsigned int)bin << 16) | (c & 0xffffu);
        }
    }
}

// ---- kernel 3: scatter keys of active buckets to their bucket's slot range (arrival order)
__global__ void k_scatter(const float* __restrict__ scores,
                          const unsigned int* __restrict__ hist,   // static exclusive prefix
                          unsigned int* __restrict__ prefw,        // working prefix (atomics)
                          unsigned long long* __restrict__ skeys) {
    int idx = blockIdx.x * 256 + threadIdx.x;
    if (idx >= B_ * N_) return;
    int b;
    unsigned long long key = make_key(scores, idx, &b);
    unsigned int b16 = (unsigned int)(key >> 48);
    if (hist[b * NBIN + b16] < (unsigned int)PRE_) {
        unsigned int slot = atomicAdd(&prefw[b * NBIN + b16], 1u);
        if (slot < SKCAP) skeys[b * SKCAP + slot] = key;
    }
}

// box decode exactly in the reference op order; no FMA contraction
__device__ __forceinline__ void compute_box(int b, unsigned int n,
                                            const float* __restrict__ deltas,
                                            const float* __restrict__ im_info,
                                            float box[4]) {
#pragma clang fp contract(off)
    int a   = (int)(n % A_);
    int pos = (int)(n / A_);
    int w   = pos % W_;
    int h   = pos / W_;
    float a0 = c_anchors[a][0] + (float)(w * 16);
    float a1 = c_anchors[a][1] + (float)(h * 16);
    float a2 = c_anchors[a][2] + (float)(w * 16);
    float a3 = c_anchors[a][3] + (float)(h * 16);
    float wa  = a2 - a0 + 1.f;
    float ha  = a3 - a1 + 1.f;
    float cxa = a0 + 0.5f * wa;
    float cya = a1 + 0.5f * ha;
    int base = ((b * 4 * A_ + a * 4) * H_ + h) * W_ + w;
    const int chs = H_ * W_;
    float dx = deltas[base];
    float dy = deltas[base + chs];
    float dw = deltas[base + 2 * chs];
    float dh = deltas[base + 3 * chs];
    float pcx = dx * wa + cxa;
    float pcy = dy * ha + cya;
    float pw  = expf(dw) * wa;
    float ph  = expf(dh) * ha;
    float x1 = pcx - 0.5f * pw;
    float y1 = pcy - 0.5f * ph;
    float x2 = pcx + 0.5f * pw;
    float y2 = pcy + 0.5f * ph;
    float imh = im_info[b * 3 + 0], imw = im_info[b * 3 + 1];
    x1 = fminf(fmaxf(x1, 0.f), imw - 1.f);
    x2 = fminf(fmaxf(x2, 0.f), imw - 1.f);
    y1 = fminf(fmaxf(y1, 0.f), imh - 1.f);
    y2 = fminf(fmaxf(y2, 0.f), imh - 1.f);
    box[0] = x1; box[1] = y1; box[2] = x2; box[3] = y2;
}

// ---- kernel 4: per-bucket exact rank-by-counting + box decode into final sorted slot
__global__ __launch_bounds__(256) void k_fixup(const unsigned long long* __restrict__ skeys,
                                               const unsigned int* __restrict__ actA,
                                               const unsigned int* __restrict__ actB,
                                               const unsigned int* __restrict__ actcnt,
                                               const float* __restrict__ deltas,
                                               const float* __restrict__ im_info,
                                               float* __restrict__ sboxes) {
    int b = blockIdx.y;
    unsigned int nact = actcnt[b];
    if (nact > ACTMAX) nact = ACTMAX;
    if (blockIdx.x >= nact) return;
    int tid = threadIdx.x;
    unsigned int start = actA[b * ACTMAX + blockIdx.x];
    unsigned int ab    = actB[b * ACTMAX + blockIdx.x];
    unsigned int cnt   = ab & 0xffffu;
    unsigned int m = cnt;
    if (start + m > SKCAP) m = SKCAP - start;
    if (m > FXCAP) m = FXCAP;
    __shared__ unsigned long long lk[FXCAP];   // 16 KB
    for (unsigned int i = tid; i < m; i += 256) lk[i] = skeys[b * SKCAP + start + i];
    __syncthreads();
    float4* sb4 = (float4*)sboxes;
    for (unsigned int e = tid; e < m; e += 256) {
        unsigned long long k = lk[e];
        unsigned int r = 0;
        for (unsigned int i = 0; i < m; ++i) r += (lk[i] < k) ? 1u : 0u;
        unsigned int pos = start + r;
        if (pos < (unsigned int)PRE_) {
            unsigned int n = (unsigned int)(k & 0xffffffffull);
            float box[4];
            compute_box(b, n, deltas, im_info, box);
            sb4[b * PRE_ + pos] = make_float4(box[0], box[1], box[2], box[3]);
        }
    }
}

__device__ __forceinline__ bool iou_gt(float4 p, float pa, float4 q, float qa) {
    float iw = fminf(p.z, q.z) - fmaxf(p.x, q.x) + 1.f;
    float ih = fminf(p.w, q.w) - fmaxf(p.y, q.y) + 1.f;
    iw = fmaxf(iw, 0.f); ih = fmaxf(ih, 0.f);
    float inter = iw * ih;
    float iou = inter / ((pa + qa) - inter);
    return iou > 0.7f;
}

// ---- kernel 5: per-window (128 candidates = sub-blocks A,B) suppression masks:
//      intraA rows (j>i in A), intraB rows (j>i in B), cross rows (A_i suppresses B_j, all j)
__global__ __launch_bounds__(64) void k_mask(const float* __restrict__ sboxes,
                                             unsigned long long* __restrict__ mask) {
    int b = blockIdx.y, w = blockIdx.x;
    int lane = threadIdx.x;
    const float4* bb = (const float4*)sboxes + b * PRE_;
    int ia = w * 128 + lane;
    int ib = w * 128 + 64 + lane;
    float4 vA = bb[ia < PRE_ ? ia : PRE_ - 1];
    float4 vB = bb[ib < PRE_ ? ib : PRE_ - 1];
    float aA = ((vA.z - vA.x) + 1.f) * ((vA.w - vA.y) + 1.f);
    float aB = ((vB.z - vB.x) + 1.f) * ((vB.w - vB.y) + 1.f);
    unsigned long long rowA = 0ull, rowB = 0ull, rowC = 0ull;
    for (int i = 0; i < 64; ++i) {
        float4 p; float pa;
        p.x = __shfl(vA.x, i); p.y = __shfl(vA.y, i);
        p.z = __shfl(vA.z, i); p.w = __shfl(vA.w, i);
        pa  = __shfl(aA, i);
        unsigned long long balA = __ballot((lane > i) && iou_gt(p, pa, vA, aA));
        unsigned long long balC = __ballot(iou_gt(p, pa, vB, aB));
        p.x = __shfl(vB.x, i); p.y = __shfl(vB.y, i);
        p.z = __shfl(vB.z, i); p.w = __shfl(vB.w, i);
        pa  = __shfl(aB, i);
        unsigned long long balB = __ballot((lane > i) && iou_gt(p, pa, vB, aB));
        if (lane == i) { rowA = balA; rowB = balB; rowC = balC; }
    }
    unsigned long long* mw = mask + (unsigned long long)(b * NW_ + w) * 192;
    mw[lane]       = rowC;   // cross row i: A_i -> B bits
    mw[64 + lane]  = rowA;   // intra-A row
    mw[128 + lane] = rowB;   // intra-B row
}

// ---- kernel 6: exact greedy NMS, pipelined, 128 candidates per iteration:
//      wave 0: delta-check both sub-blocks vs last window's new keeps, then mask-resolve
//      A, propagate cross suppression, resolve B. waves 1-15: kept-list check for the
//      next window (both sub-blocks per lane). One barrier/iteration.
__global__ __launch_bounds__(1024) void k_nms(const float* __restrict__ sboxes,
                                              const unsigned long long* __restrict__ mask,
                                              float* __restrict__ out) {
    int b = blockIdx.x;
    int tid = threadIdx.x;
    int lane = tid & 63;
    int wave = tid >> 6;                     // 0..15
    __shared__ float4 s_box[POST_ + 128];
    __shared__ float  s_ar [POST_ + 128];
    __shared__ unsigned long long s_pend[2][16][2];
    __shared__ int s_cnt[2];
    __shared__ int s_final;
    if (tid < 64) ((unsigned long long*)s_pend)[tid] = 0ull;
    if (tid < 2) s_cnt[tid] = 0;
    if (tid == 0) s_final = 0;
    __syncthreads();

    const float4* bb = (const float4*)sboxes + b * PRE_;
    float* ob = out + b * POST_ * 5;

    // register prefetch: wave0 holds window 0 (+3 mask rows); waves 1-15 hold window 1
    float4 vmeA, vmeB;
    unsigned long long rA = 0ull, rB = 0ull, rC = 0ull;
    if (wave == 0) {
        vmeA = bb[lane];
        vmeB = bb[64 + lane];
        const unsigned long long* mw = mask + (unsigned long long)(b * NW_) * 192;
        rC = mw[lane]; rA = mw[64 + lane]; rB = mw[128 + lane];
    } else {
        int ja = 128 + lane, jb = 192 + lane;
        vmeA = bb[ja]; vmeB = bb[jb];
    }

    for (int k = 0; k < NW_; ++k) {
        int Cm1 = s_cnt[(k + 1) & 1];         // kept count through window k-1
        if (Cm1 >= POST_) break;
        if (wave == 0) {
            int ia = k * 128 + lane, ib = k * 128 + 64 + lane;
            float4 vA = vmeA, vB = vmeB;
            unsigned long long rowA = rA, rowB = rB, rowC = rC;
            bool validA = ia < PRE_, validB = ib < PRE_;
            if (k + 1 < NW_) {                 // prefetch window k+1
                int na = (k + 1) * 128 + lane, nb = na + 64;
                vmeA = bb[na < PRE_ ? na : PRE_ - 1];
                vmeB = bb[nb < PRE_ ? nb : PRE_ - 1];
                const unsigned long long* mw = mask + (unsigned long long)(b * NW_ + k + 1) * 192;
                rC = mw[lane]; rA = mw[64 + lane]; rB = mw[128 + lane];
            }
            float aA = ((vA.z - vA.x) + 1.f) * ((vA.w - vA.y) + 1.f);
            float aB = ((vB.z - vB.x) + 1.f) * ((vB.w - vB.y) + 1.f);
            int Cm2 = s_cnt[k & 1];            // kept count through window k-2
            bool supA = !validA, supB = !validB;
            for (int kk = Cm2; kk < Cm1; ++kk) {   // delta: keeps added by window k-1
                float4 kb = s_box[kk];
                float ka = s_ar[kk];
                supA = supA | iou_gt(vA, aA, kb, ka);
                supB = supB | iou_gt(vB, aB, kb, ka);
            }
            unsigned long long supmA = __ballot(supA);
            unsigned long long supmB = __ballot(supB);
            const unsigned long long (*pnd)[2] = s_pend[k & 1];
#pragma unroll
            for (int w2 = 1; w2 < 16; ++w2) { supmA |= pnd[w2][0]; supmB |= pnd[w2][1]; }
            unsigned int alo = (unsigned int)rowA, ahi = (unsigned int)(rowA >> 32);
            unsigned int blo = (unsigned int)rowB, bhi = (unsigned int)(rowB >> 32);
            unsigned int clo = (unsigned int)rowC, chi = (unsigned int)(rowC >> 32);
            // resolve A; accumulate cross-suppression into B
            unsigned long long alive = ~supmA;
            unsigned long long keepA = 0ull;
            unsigned long long bsup = supmB;
            while (alive) {
                int i = __builtin_ctzll(alive);
                keepA |= (1ull << i);
                alive &= ~(1ull << i);
                unsigned long long mlo = (unsigned int)__builtin_amdgcn_readlane((int)alo, i);
                unsigned long long mhi = (unsigned int)__builtin_amdgcn_readlane((int)ahi, i);
                alive &= ~((mhi << 32) | mlo);
                unsigned long long xlo = (unsigned int)__builtin_amdgcn_readlane((int)clo, i);
                unsigned long long xhi = (unsigned int)__builtin_amdgcn_readlane((int)chi, i);
                bsup |= (xhi << 32) | xlo;
            }
            // resolve B
            unsigned long long aliveB = ~bsup;
            unsigned long long keepB = 0ull;
            while (aliveB) {
                int i = __builtin_ctzll(aliveB);
                keepB |= (1ull << i);
                aliveB &= ~(1ull << i);
                unsigned long long mlo = (unsigned int)__builtin_amdgcn_readlane((int)blo, i);
                unsigned long long mhi = (unsigned int)__builtin_amdgcn_readlane((int)bhi, i);
                aliveB &= ~((mhi << 32) | mlo);
            }
            int nA = __builtin_popcountll(keepA);
            if ((keepA >> lane) & 1ull) {
                int my = Cm1 + __builtin_popcountll(keepA & ((1ull << lane) - 1ull));
                s_box[my] = vA; s_ar[my] = aA;
                if (my < POST_) {
                    ob[my * 5 + 0] = (float)b;
                    ob[my * 5 + 1] = vA.x; ob[my * 5 + 2] = vA.y;
                    ob[my * 5 + 3] = vA.z; ob[my * 5 + 4] = vA.w;
                }
            }
            if ((keepB >> lane) & 1ull) {
                int my = Cm1 + nA + __builtin_popcountll(keepB & ((1ull << lane) - 1ull));
                s_box[my] = vB; s_ar[my] = aB;
                if (my < POST_) {
                    ob[my * 5 + 0] = (float)b;
                    ob[my * 5 + 1] = vB.x; ob[my * 5 + 2] = vB.y;
                    ob[my * 5 + 3] = vB.z; ob[my * 5 + 4] = vB.w;
                }
            }
            if (lane == 0) {
                int nc = Cm1 + nA + __builtin_popcountll(keepB);
                s_cnt[k & 1] = nc;
                s_final = nc;
            }
        } else if (k + 1 < NW_) {
            // phase-a for window k+1 vs kept[0..Cm1)
            int ja = (k + 1) * 128 + lane, jb = ja + 64;
            float4 vA2 = vmeA, vB2 = vmeB;
            bool validA2 = ja < PRE_, validB2 = jb < PRE_;
            if (k + 2 < NW_) {                 // prefetch window k+2
                int na = (k + 2) * 128 + lane, nb = na + 64;
                vmeA = bb[na < PRE_ ? na : PRE_ - 1];
                vmeB = bb[nb < PRE_ ? nb : PRE_ - 1];
            }
            float aA2 = ((vA2.z - vA2.x) + 1.f) * ((vA2.w - vA2.y) + 1.f);
            float aB2 = ((vB2.z - vB2.x) + 1.f) * ((vB2.w - vB2.y) + 1.f);
            bool supA2 = !validA2, supB2 = !validB2;
            for (int kk = wave - 1; kk < Cm1; kk += 15) {
                float4 kb = s_box[kk];
                float ka = s_ar[kk];
                supA2 = supA2 | iou_gt(vA2, aA2, kb, ka);
                supB2 = supB2 | iou_gt(vB2, aB2, kb, ka);
            }
            unsigned long long balA = __ballot(supA2);
            unsigned long long balB = __ballot(supB2);
            if (lane == 0) {
                s_pend[(k + 1) & 1][wave][0] = balA;
                s_pend[(k + 1) & 1][wave][1] = balB;
            }
        }
        __syncthreads();
    }
    __syncthreads();
    int kept = s_final;
    int start = kept < POST_ ? kept : POST_;
    for (int r = start + tid; r < POST_; r += 1024) {
        ob[r * 5 + 0] = (float)b;
        ob[r * 5 + 1] = 0.f; ob[r * 5 + 2] = 0.f;
        ob[r * 5 + 3] = 0.f; ob[r * 5 + 4] = 0.f;
    }
}

extern "C" void kernel_launch(void* const* d_in, const int* in_sizes, int n_in,
                              void* d_out, int out_size, void* d_ws, size_t ws_size,
                              hipStream_t stream) {
    const float* scores  = (const float*)d_in[0];
    const float* deltas  = (const float*)d_in[1];
    const float* im_info = (const float*)d_in[2];
    float* out = (float*)d_out;

    // workspace layout (16-aligned blocks). maskb OVERLAPS hist: hist is dead after
    // k_scatter, k_mask runs later in the same stream (replay-safe: memset re-zeros).
    char* ws = (char*)d_ws;
    unsigned int*       hist    = (unsigned int*)      (ws);             // 1,048,576
    unsigned long long* maskb   = (unsigned long long*)(ws);             //   288,768 (reuse)
    unsigned int*       prefw   = (unsigned int*)      (ws + 1048576);   // 1,048,576
    unsigned long long* skeys   = (unsigned long long*)(ws + 2097152);   //   262,144
    unsigned int*       segsum  = (unsigned int*)      (ws + 2359296);   //     4,096
    unsigned int*       segbase = (unsigned int*)      (ws + 2363392);   //     4,096
    unsigned int*       actA    = (unsigned int*)      (ws + 2367488);   //     4,096
    unsigned int*       actB    = (unsigned int*)      (ws + 2371584);   //     4,096
    unsigned int*       actcnt  = (unsigned int*)      (ws + 2375680);   //        32
    float*              sbx     = (float*)             (ws + 2375712);   //   384,000

    hipMemsetAsync(hist, 0, B_ * NBIN * sizeof(unsigned int), stream);
    hipMemsetAsync(actcnt, 0, B_ * sizeof(unsigned int), stream);

    const int total = B_ * N_;
    dim3 sgrid(NSEG, B_);
    k_hist<<<(total + 255) / 256, 256, 0, stream>>>(scores, hist);
    k_prefix1<<<sgrid, 256, 0, stream>>>(hist, segsum);
    k_prefix2<<<B_, 256, 0, stream>>>(segsum, segbase);
    k_prefix3<<<sgrid, 256, 0, stream>>>(hist, segbase, prefw, actA, actB, actcnt);
    k_scatter<<<(total + 255) / 256, 256, 0, stream>>>(scores, hist, prefw, skeys);
    dim3 fgrid(ACTMAX, B_);
    k_fixup<<<fgrid, 256, 0, stream>>>(skeys, actA, actB, actcnt, deltas, im_info, sbx);
    dim3 mgrid(NW_, B_);
    k_mask<<<mgrid, 64, 0, stream>>>(sbx, maskb);
    k_nms<<<B_, 1024, 0, stream>>>(sbx, maskb, out);
}

// Round 9
// 127.248 us; speedup vs baseline: 1.1655x; 1.1655x over previous
//
#include <hip/hip_runtime.h>
#include <stdint.h>

#define B_     4
#define A_     9
#define H_     50
#define W_     76
#define N_     (H_ * W_ * A_)   // 34200
#define PRE_   6000
#define POST_  300
#define NBIN   16384
#define BINOFF 0xC000
#define NSEG   64
#define SKCAP  8192
#define ACTMAX 256
#define FXCAP  2048
#define NB_    94               // ceil(PRE_/64)

// generate_anchors(16) precomputed (exact, verified against the numpy code)
__constant__ float c_anchors[9][4] = {
    { -84.f,  -40.f,  99.f,  55.f},
    {-176.f,  -88.f, 191.f, 103.f},
    {-360.f, -184.f, 375.f, 199.f},
    { -56.f,  -56.f,  71.f,  71.f},
    {-120.f, -120.f, 135.f, 135.f},
    {-248.f, -248.f, 263.f, 263.f},
    { -36.f,  -80.f,  51.f,  95.f},
    { -80.f, -168.f,  95.f, 183.f},
    {-168.f, -344.f, 183.f, 359.f},
};

// composite key: (~score_bits)<<32 | n  — ascending key == descending score, ascending idx
__device__ __forceinline__ unsigned long long make_key(const float* __restrict__ scores,
                                                       int idx, int* pb) {
    int w = idx % W_;
    int h = (idx / W_) % H_;
    int a = (idx / (W_ * H_)) % A_;
    int b = idx / (W_ * H_ * A_);
    float s = scores[(((b * 2 * A_) + A_ + a) * H_ + h) * W_ + w];
    unsigned int sb = __float_as_uint(s);          // s >= 0 -> monotone bits
    unsigned int n  = (unsigned int)((h * W_ + w) * A_ + a);
    *pb = b;
    return (((unsigned long long)(~sb)) << 32) | (unsigned long long)n;
}

// scores in [0,1) -> top16 of key in [0xC080,0xFFFF]; clamp is monotone (exactness kept
// by full-key rank within bucket), only bucket-capacity relies on the [0,1) range.
__device__ __forceinline__ int key_bin(unsigned long long key) {
    int bin = (int)(unsigned int)(key >> 48) - BINOFF;
    return bin < 0 ? 0 : bin;
}

// ---- kernel 1: binned histogram of keys
__global__ void k_hist(const float* __restrict__ scores,
                       unsigned int* __restrict__ hist) {
    int idx = blockIdx.x * 256 + threadIdx.x;
    if (idx >= B_ * N_) return;
    int b;
    unsigned long long key = make_key(scores, idx, &b);
    atomicAdd(&hist[b * NBIN + key_bin(key)], 1u);
}

// ---- kernel 2a: per-segment sums (coalesced), 256 bins per block
__global__ __launch_bounds__(256) void k_prefix1(const unsigned int* __restrict__ hist,
                                                 unsigned int* __restrict__ segsum) {
    int b = blockIdx.y, seg = blockIdx.x, tid = threadIdx.x;
    int lane = tid & 63, wid = tid >> 6;
    unsigned int v = hist[b * NBIN + seg * 256 + tid];
#pragma unroll
    for (int off = 32; off > 0; off >>= 1) v += __shfl_down(v, off);
    __shared__ unsigned int wsum[4];
    if (lane == 0) wsum[wid] = v;
    __syncthreads();
    if (tid == 0) segsum[b * NSEG + seg] = wsum[0] + wsum[1] + wsum[2] + wsum[3];
}

// ---- kernel 2b: segment-base wave-scan (64 segsums) fused with intra-segment scan;
//      coalesced prefix writes; append active buckets (cnt>0 && start<PRE_)
__global__ __launch_bounds__(256) void k_prefix3(unsigned int* __restrict__ hist,
                                                 const unsigned int* __restrict__ segsum,
                                                 unsigned int* __restrict__ prefw,
                                                 unsigned int* __restrict__ actA,
                                                 unsigned int* __restrict__ actB,
                                                 unsigned int* __restrict__ actcnt) {
    int b = blockIdx.y, seg = blockIdx.x, tid = threadIdx.x;
    int lane = tid & 63;
    // every wave redundantly: exclusive base of this segment via 64-lane wave scan
    unsigned int sv = segsum[b * NSEG + lane];
    unsigned int inc = sv;
#pragma unroll
    for (int off = 1; off < 64; off <<= 1) {
        unsigned int t = __shfl_up(inc, off);
        if (lane >= off) inc += t;
    }
    unsigned int segbase = __shfl(inc, seg) - __shfl(sv, seg);
    // intra-segment 256-wide scan
    int bin = seg * 256 + tid;
    unsigned int c = hist[b * NBIN + bin];
    __shared__ unsigned int sp[256];
    sp[tid] = c;
    __syncthreads();
    for (int off = 1; off < 256; off <<= 1) {
        unsigned int v = (tid >= off) ? sp[tid - off] : 0u;
        __syncthreads();
        sp[tid] += v;
        __syncthreads();
    }
    unsigned int run = segbase + sp[tid] - c;   // global exclusive prefix
    hist[b * NBIN + bin]  = run;    // static prefix (coalesced)
    prefw[b * NBIN + bin] = run;    // working prefix (coalesced)
    if (c > 0 && run < (unsigned int)PRE_) {
        unsigned int pos = atomicAdd(&actcnt[b], 1u);
        if (pos < ACTMAX) {
            actA[b * ACTMAX + pos] = run;
            actB[b * ACTMAX + pos] = ((unsigned int)bin << 16) | (c & 0xffffu);
        }
    }
}

// ---- kernel 3: scatter keys of active buckets to their bucket's slot range (arrival order)
__global__ void k_scatter(const float* __restrict__ scores,
                          const unsigned int* __restrict__ hist,   // static exclusive prefix
                          unsigned int* __restrict__ prefw,        // working prefix (atomics)
                          unsigned long long* __restrict__ skeys) {
    int idx = blockIdx.x * 256 + threadIdx.x;
    if (idx >= B_ * N_) return;
    int b;
    unsigned long long key = make_key(scores, idx, &b);
    int bin = key_bin(key);
    if (hist[b * NBIN + bin] < (unsigned int)PRE_) {
        unsigned int slot = atomicAdd(&prefw[b * NBIN + bin], 1u);
        if (slot < SKCAP) skeys[b * SKCAP + slot] = key;
    }
}

// box decode exactly in the reference op order; no FMA contraction
__device__ __forceinline__ void compute_box(int b, unsigned int n,
                                            const float* __restrict__ deltas,
                                            const float* __restrict__ im_info,
                                            float box[4]) {
#pragma clang fp contract(off)
    int a   = (int)(n % A_);
    int pos = (int)(n / A_);
    int w   = pos % W_;
    int h   = pos / W_;
    float a0 = c_anchors[a][0] + (float)(w * 16);
    float a1 = c_anchors[a][1] + (float)(h * 16);
    float a2 = c_anchors[a][2] + (float)(w * 16);
    float a3 = c_anchors[a][3] + (float)(h * 16);
    float wa  = a2 - a0 + 1.f;
    float ha  = a3 - a1 + 1.f;
    float cxa = a0 + 0.5f * wa;
    float cya = a1 + 0.5f * ha;
    int base = ((b * 4 * A_ + a * 4) * H_ + h) * W_ + w;
    const int chs = H_ * W_;
    float dx = deltas[base];
    float dy = deltas[base + chs];
    float dw = deltas[base + 2 * chs];
    float dh = deltas[base + 3 * chs];
    float pcx = dx * wa + cxa;
    float pcy = dy * ha + cya;
    float pw  = expf(dw) * wa;
    float ph  = expf(dh) * ha;
    float x1 = pcx - 0.5f * pw;
    float y1 = pcy - 0.5f * ph;
    float x2 = pcx + 0.5f * pw;
    float y2 = pcy + 0.5f * ph;
    float imh = im_info[b * 3 + 0], imw = im_info[b * 3 + 1];
    x1 = fminf(fmaxf(x1, 0.f), imw - 1.f);
    x2 = fminf(fmaxf(x2, 0.f), imw - 1.f);
    y1 = fminf(fmaxf(y1, 0.f), imh - 1.f);
    y2 = fminf(fmaxf(y2, 0.f), imh - 1.f);
    box[0] = x1; box[1] = y1; box[2] = x2; box[3] = y2;
}

// ---- kernel 4: per-bucket exact rank-by-counting + box decode into final sorted slot
__global__ __launch_bounds__(256) void k_fixup(const unsigned long long* __restrict__ skeys,
                                               const unsigned int* __restrict__ actA,
                                               const unsigned int* __restrict__ actB,
                                               const unsigned int* __restrict__ actcnt,
                                               const float* __restrict__ deltas,
                                               const float* __restrict__ im_info,
                                               float* __restrict__ sboxes) {
    int b = blockIdx.y;
    unsigned int nact = actcnt[b];
    if (nact > ACTMAX) nact = ACTMAX;
    if (blockIdx.x >= nact) return;
    int tid = threadIdx.x;
    unsigned int start = actA[b * ACTMAX + blockIdx.x];
    unsigned int ab    = actB[b * ACTMAX + blockIdx.x];
    unsigned int cnt   = ab & 0xffffu;
    unsigned int m = cnt;
    if (start + m > SKCAP) m = SKCAP - start;
    if (m > FXCAP) m = FXCAP;
    __shared__ unsigned long long lk[FXCAP];   // 16 KB
    for (unsigned int i = tid; i < m; i += 256) lk[i] = skeys[b * SKCAP + start + i];
    __syncthreads();
    float4* sb4 = (float4*)sboxes;
    for (unsigned int e = tid; e < m; e += 256) {
        unsigned long long k = lk[e];
        unsigned int r = 0;
        for (unsigned int i = 0; i < m; ++i) r += (lk[i] < k) ? 1u : 0u;
        unsigned int pos = start + r;
        if (pos < (unsigned int)PRE_) {
            unsigned int n = (unsigned int)(k & 0xffffffffull);
            float box[4];
            compute_box(b, n, deltas, im_info, box);
            sb4[b * PRE_ + pos] = make_float4(box[0], box[1], box[2], box[3]);
        }
    }
}

// ---- kernel 5: per-block 64x64 intra-block suppression masks (fully parallel)
//      mask row i, bit j = (j > i) && IoU(i,j) > 0.7   (identical float expr to NMS)
__global__ __launch_bounds__(64) void k_mask(const float* __restrict__ sboxes,
                                             unsigned long long* __restrict__ mask) {
    int b = blockIdx.y, blk = blockIdx.x;
    int lane = threadIdx.x;
    const float4* bb = (const float4*)sboxes + b * PRE_;
    int idx = blk * 64 + lane;
    float4 v = bb[idx < PRE_ ? idx : PRE_ - 1];
    float area = ((v.z - v.x) + 1.f) * ((v.w - v.y) + 1.f);
    unsigned long long myrow = 0ull;
    for (int i = 0; i < 64; ++i) {
        float ix1 = __shfl(v.x, i), iy1 = __shfl(v.y, i);
        float ix2 = __shfl(v.z, i), iy2 = __shfl(v.w, i);
        float iar = __shfl(area, i);
        float iw = fminf(v.z, ix2) - fmaxf(v.x, ix1) + 1.f;
        float ih = fminf(v.w, iy2) - fmaxf(v.y, iy1) + 1.f;
        iw = fmaxf(iw, 0.f); ih = fmaxf(ih, 0.f);
        float inter = iw * ih;
        float iou = inter / ((area + iar) - inter);
        unsigned long long bal = __ballot((lane > i) && (iou > 0.7f));
        if (lane == i) myrow = bal;
    }
    mask[(b * NB_ + blk) * 64 + lane] = myrow;
}

// ---- kernel 6: exact greedy NMS, pipelined:
//      wave 0 resolves block k (delta-check vs block k-1's new keeps + mask resolve),
//      waves 1-15 concurrently run the long kept-list check for block k+1.
//      One barrier per iteration; parity-double-buffered LDS hand-off slots.
__global__ __launch_bounds__(1024) void k_nms(const float* __restrict__ sboxes,
                                              const unsigned long long* __restrict__ mask,
                                              float* __restrict__ out) {
    int b = blockIdx.x;
    int tid = threadIdx.x;
    int lane = tid & 63;
    int wave = tid >> 6;                     // 0..15
    __shared__ float4 s_box[POST_ + 64];
    __shared__ float  s_ar [POST_ + 64];
    __shared__ unsigned long long s_pend[2][16];
    __shared__ int s_cnt[2];
    __shared__ int s_final;
    if (tid < 32) ((unsigned long long*)s_pend)[tid] = 0ull;
    if (tid < 2) s_cnt[tid] = 0;
    if (tid == 0) s_final = 0;
    __syncthreads();

    const float4* bb = (const float4*)sboxes + b * PRE_;
    float* ob = out + b * POST_ * 5;

    // register prefetch: wave0 holds block 0 (+mask row); waves 1-15 hold block 1
    float4 vme;
    unsigned long long rowme = 0ull;
    if (wave == 0) {
        vme = bb[lane];                       // block 0 (64 <= PRE_, all valid)
        rowme = mask[(b * NB_ + 0) * 64 + lane];
    } else {
        vme = bb[64 + lane];                  // block 1
    }

    for (int k = 0; k < NB_; ++k) {
        int Cm1 = s_cnt[(k + 1) & 1];         // kept count through block k-1
        if (Cm1 >= POST_) break;
        if (wave == 0) {
            int idx = k * 64 + lane;
            bool valid = idx < PRE_;
            float4 v = vme;
            unsigned long long row = rowme;
            if (k + 1 < NB_) {                 // prefetch block k+1
                int nidx = (k + 1) * 64 + lane;
                vme = bb[nidx < PRE_ ? nidx : PRE_ - 1];
                rowme = mask[(b * NB_ + k + 1) * 64 + lane];
            }
            float area = ((v.z - v.x) + 1.f) * ((v.w - v.y) + 1.f);
            int Cm2 = s_cnt[k & 1];           // kept count through block k-2
            bool sup = !valid;
            for (int kk = Cm2; kk < Cm1; ++kk) {   // delta: keeps added by block k-1
                float4 kb = s_box[kk];
                float iw = fminf(v.z, kb.z) - fmaxf(v.x, kb.x) + 1.f;
                float ih = fminf(v.w, kb.w) - fmaxf(v.y, kb.y) + 1.f;
                iw = fmaxf(iw, 0.f); ih = fmaxf(ih, 0.f);
                float inter = iw * ih;
                float iou = inter / ((area + s_ar[kk]) - inter);
                sup = sup | (iou > 0.7f);
            }
            unsigned long long supm = __ballot(sup);
            const unsigned long long* pnd = s_pend[k & 1];
#pragma unroll
            for (int w2 = 1; w2 < 16; ++w2) supm |= pnd[w2];
            unsigned int rlo = (unsigned int)row;
            unsigned int rhi = (unsigned int)(row >> 32);
            unsigned long long alive = ~supm;
            unsigned long long keepm = 0ull;
            while (alive) {
                int i = __builtin_ctzll(alive);     // uniform across wave 0
                keepm |= (1ull << i);
                alive &= ~(1ull << i);
                unsigned long long mlo = (unsigned int)__builtin_amdgcn_readlane((int)rlo, i);
                unsigned long long mhi = (unsigned int)__builtin_amdgcn_readlane((int)rhi, i);
                alive &= ~((mhi << 32) | mlo);
            }
            if ((keepm >> lane) & 1ull) {
                int my = Cm1 + __builtin_popcountll(keepm & ((1ull << lane) - 1ull));
                s_box[my] = v;
                s_ar [my] = area;
                if (my < POST_) {
                    ob[my * 5 + 0] = (float)b;
                    ob[my * 5 + 1] = v.x; ob[my * 5 + 2] = v.y;
                    ob[my * 5 + 3] = v.z; ob[my * 5 + 4] = v.w;
                }
            }
            if (lane == 0) {
                int nc = Cm1 + __builtin_popcountll(keepm);
                s_cnt[k & 1] = nc;
                s_final = nc;
            }
        } else if (k + 1 < NB_) {
            // phase-a for block k+1 vs kept[0..Cm1) (gap covered by wave0's delta next iter)
            int jdx = (k + 1) * 64 + lane;
            bool valid2 = jdx < PRE_;
            float4 v2 = vme;
            if (k + 2 < NB_) {                 // prefetch block k+2
                int nj = (k + 2) * 64 + lane;
                vme = bb[nj < PRE_ ? nj : PRE_ - 1];
            }
            float area2 = ((v2.z - v2.x) + 1.f) * ((v2.w - v2.y) + 1.f);
            bool sup2 = !valid2;
            for (int kk = wave - 1; kk < Cm1; kk += 15) {
                float4 kb = s_box[kk];
                float iw = fminf(v2.z, kb.z) - fmaxf(v2.x, kb.x) + 1.f;
                float ih = fminf(v2.w, kb.w) - fmaxf(v2.y, kb.y) + 1.f;
                iw = fmaxf(iw, 0.f); ih = fmaxf(ih, 0.f);
                float inter = iw * ih;
                float iou = inter / ((area2 + s_ar[kk]) - inter);
                sup2 = sup2 | (iou > 0.7f);
            }
            unsigned long long bal = __ballot(sup2);
            if (lane == 0) s_pend[(k + 1) & 1][wave] = bal;
        }
        __syncthreads();
    }
    __syncthreads();
    int kept = s_final;
    int start = kept < POST_ ? kept : POST_;
    for (int r = start + tid; r < POST_; r += 1024) {
        ob[r * 5 + 0] = (float)b;
        ob[r * 5 + 1] = 0.f; ob[r * 5 + 2] = 0.f;
        ob[r * 5 + 3] = 0.f; ob[r * 5 + 4] = 0.f;
    }
}

extern "C" void kernel_launch(void* const* d_in, const int* in_sizes, int n_in,
                              void* d_out, int out_size, void* d_ws, size_t ws_size,
                              hipStream_t stream) {
    const float* scores  = (const float*)d_in[0];
    const float* deltas  = (const float*)d_in[1];
    const float* im_info = (const float*)d_in[2];
    float* out = (float*)d_out;

    // workspace layout (16-aligned blocks). maskb OVERLAPS hist: hist is dead after
    // k_scatter; k_mask runs later in the same stream (replay-safe: memset re-zeros).
    char* ws = (char*)d_ws;
    unsigned int*       hist    = (unsigned int*)      (ws);             // 262,144
    unsigned long long* maskb   = (unsigned long long*)(ws);             // 192,512 (reuse)
    unsigned int*       prefw   = (unsigned int*)      (ws + 262144);    // 262,144
    unsigned long long* skeys   = (unsigned long long*)(ws + 524288);    // 262,144
    unsigned int*       segsum  = (unsigned int*)      (ws + 786432);    //   1,024
    unsigned int*       actA    = (unsigned int*)      (ws + 787456);    //   4,096
    unsigned int*       actB    = (unsigned int*)      (ws + 791552);    //   4,096
    unsigned int*       actcnt  = (unsigned int*)      (ws + 795648);    //      32
    float*              sbx     = (float*)             (ws + 795680);    // 384,000

    hipMemsetAsync(hist, 0, B_ * NBIN * sizeof(unsigned int), stream);
    hipMemsetAsync(actcnt, 0, B_ * sizeof(unsigned int), stream);

    const int total = B_ * N_;
    dim3 sgrid(NSEG, B_);
    k_hist<<<(total + 255) / 256, 256, 0, stream>>>(scores, hist);
    k_prefix1<<<sgrid, 256, 0, stream>>>(hist, segsum);
    k_prefix3<<<sgrid, 256, 0, stream>>>(hist, segsum, prefw, actA, actB, actcnt);
    k_scatter<<<(total + 255) / 256, 256, 0, stream>>>(scores, hist, prefw, skeys);
    dim3 fgrid(ACTMAX, B_);
    k_fixup<<<fgrid, 256, 0, stream>>>(skeys, actA, actB, actcnt, deltas, im_info, sbx);
    dim3 mgrid(NB_, B_);
    k_mask<<<mgrid, 64, 0, stream>>>(sbx, maskb);
    k_nms<<<B_, 1024, 0, stream>>>(sbx, maskb, out);
}